// Round 6
// baseline (351.927 us; speedup 1.0000x reference)
//
#include <hip/hip_runtime.h>

#define NN 100000
#define NE 1600000
#define NB 391              // ceil(NN/256) node-buckets of 256
#define NBP 512             // padded bucket count (pow2 scans)
#define CHUNK 8192
#define NCHUNK 196          // ceil(NE/CHUNK)

static __device__ __forceinline__ unsigned short f2bf(float f) {
    unsigned u = __float_as_uint(f);
    u += 0x7fffu + ((u >> 16) & 1u);   // RNE
    return (unsigned short)(u >> 16);
}

// ---- KA: per-chunk bucket histogram rows (block-owned, no atomics/zeroing) ----
__global__ __launch_bounds__(256) void hist_rows(const int* __restrict__ dst,
                                                 int* __restrict__ C) {
    __shared__ int h[NBP];
    int t = threadIdx.x;
    h[t] = 0; h[t + 256] = 0;
    __syncthreads();
    int base = blockIdx.x * CHUNK;
    int end = min(base + CHUNK, NE);
    for (int e = base + t; e < end; e += 256) atomicAdd(&h[dst[e] >> 8], 1);
    __syncthreads();
    C[blockIdx.x * NBP + t] = h[t];
    C[blockIdx.x * NBP + t + 256] = h[t + 256];
}

// ---- KB: single block: bucket totals -> bbase; rewrite C to global offsets ----
__global__ __launch_bounds__(512) void offsets_k(int* __restrict__ C,
                                                 int* __restrict__ bbase) {
    __shared__ int buf[2][512];
    int t = threadIdx.x;
    int tot = 0;
    for (int c0 = 0; c0 < NCHUNK; c0 += 8) {
        int v[8];
        #pragma unroll
        for (int j = 0; j < 8; ++j) {
            int cc = c0 + j;
            v[j] = (cc < NCHUNK) ? C[cc * NBP + t] : 0;   // 8 loads in flight
        }
        #pragma unroll
        for (int j = 0; j < 8; ++j) tot += v[j];
    }
    int pi = 0; buf[0][t] = tot; __syncthreads();
    for (int off = 1; off < 512; off <<= 1) {
        int add = (t >= off) ? buf[pi][t - off] : 0;
        buf[1 - pi][t] = buf[pi][t] + add; pi ^= 1; __syncthreads();
    }
    int ex = buf[pi][t] - tot;
    bbase[t] = ex;
    if (t == 511) bbase[512] = buf[pi][511];   // == NE
    int run = ex;
    for (int c0 = 0; c0 < NCHUNK; c0 += 8) {
        int v[8];
        #pragma unroll
        for (int j = 0; j < 8; ++j) {
            int cc = c0 + j;
            v[j] = (cc < NCHUNK) ? C[cc * NBP + t] : 0;
        }
        #pragma unroll
        for (int j = 0; j < 8; ++j) {
            int cc = c0 + j;
            if (cc < NCHUNK) { C[cc * NBP + t] = run; run += v[j]; }
        }
    }
    C[NCHUNK * NBP + t] = run;   // row 196 = region ends (for place's row-diff)
}

// ---- KC: placement, LDS binning, offsets from C (no global atomics) ----
__global__ __launch_bounds__(512) void place_k(const int* __restrict__ src,
                                               const int* __restrict__ dst,
                                               const int* __restrict__ C,
                                               int* __restrict__ pairs) {
    __shared__ int stage[CHUNK];
    __shared__ int sbuf[2][512];
    __shared__ int lex[512];
    __shared__ int gbase[512];
    __shared__ int lnext[512];
    int t = threadIdx.x;
    int c = blockIdx.x;
    int off0 = C[c * NBP + t];
    int cnt = C[(c + 1) * NBP + t] - off0;
    gbase[t] = off0;
    int pi = 0; sbuf[0][t] = cnt; __syncthreads();
    for (int off = 1; off < 512; off <<= 1) {
        int add = (t >= off) ? sbuf[pi][t - off] : 0;
        sbuf[1 - pi][t] = sbuf[pi][t] + add; pi ^= 1; __syncthreads();
    }
    int ex = sbuf[pi][t] - cnt;
    lex[t] = ex; lnext[t] = ex;
    __syncthreads();
    int base = c * CHUNK;
    int end = min(base + CHUNK, NE);
    for (int e = base + t; e < end; e += 512) {
        int d = dst[e];
        int r = atomicAdd(&lnext[d >> 8], 1);
        stage[r] = src[e] | ((d & 255) << 17);
    }
    __syncthreads();
    int cc = end - base;
    for (int i = t; i < cc; i += 512) {
        int lo = 0, hi = 511;
        while (lo < hi) {
            int mid = (lo + hi + 1) >> 1;
            if (lex[mid] <= i) lo = mid; else hi = mid - 1;
        }
        pairs[gbase[lo] + (i - lex[lo])] = stage[i];
    }
}

// ---- KD: per-bucket CSR build + dinv ----
__global__ __launch_bounds__(256) void bkt_csr(const int* __restrict__ pairs,
                                               const int* __restrict__ base,
                                               int* __restrict__ next,
                                               float* __restrict__ dinv,
                                               int* __restrict__ esrc) {
    __shared__ int cnt[256];
    __shared__ int sbuf[2][256];
    __shared__ int nxt[256];
    int b = blockIdx.x;
    int e0 = base[b], e1 = base[b + 1];
    int t = threadIdx.x;
    cnt[t] = 0;
    __syncthreads();
    for (int i = e0 + t; i < e1; i += 256) atomicAdd(&cnt[pairs[i] >> 17], 1);
    __syncthreads();
    int v = cnt[t];
    int pi = 0; sbuf[0][t] = v; __syncthreads();
    for (int off = 1; off < 256; off <<= 1) {
        int add = (t >= off) ? sbuf[pi][t - off] : 0;
        sbuf[1 - pi][t] = sbuf[pi][t] + add; pi ^= 1; __syncthreads();
    }
    int incl = sbuf[pi][t];
    int node = b * 256 + t;
    if (node < NN) {
        next[node] = e0 + incl;
        dinv[node] = rsqrtf((float)v + 1.0f);
    }
    nxt[t] = e0 + incl - v;
    __syncthreads();
    for (int i = e0 + t; i < e1; i += 256) {
        int w = pairs[i];
        int p = atomicAdd(&nxt[w >> 17], 1);
        esrc[p] = w & 0x1FFFF;
    }
}

// ---- KE: GEMM [n,64]@[64,64] -> bf16 g = acc*dinv ----
__global__ __launch_bounds__(256) void gemm64g(const float* __restrict__ X,
                                               const float* __restrict__ W,
                                               const float* __restrict__ dinv,
                                               ushort4* __restrict__ G, int n) {
    __shared__ float4 Ws[64][16];
    __shared__ float  Xs[16][68];
    int tid = threadIdx.x;
    const float4* W4 = (const float4*)W;
    #pragma unroll
    for (int i = tid; i < 64 * 16; i += 256) Ws[i >> 4][i & 15] = W4[i];
    {
        int rr = tid >> 4, q = tid & 15;
        int node = blockIdx.x * 16 + rr;
        float4 v = ((const float4*)(X + (size_t)node * 64))[q];
        *(float4*)&Xs[rr][q * 4] = v;
    }
    __syncthreads();
    int r = tid >> 4, cq = tid & 15;
    float4 acc = {0.f, 0.f, 0.f, 0.f};
    #pragma unroll
    for (int k = 0; k < 64; ++k) {
        float x  = Xs[r][k];
        float4 w = Ws[k][cq];
        acc.x += x * w.x; acc.y += x * w.y; acc.z += x * w.z; acc.w += x * w.w;
    }
    int node = blockIdx.x * 16 + r;
    float dd = dinv[node];
    ushort4 pk;
    pk.x = f2bf(acc.x * dd); pk.y = f2bf(acc.y * dd);
    pk.z = f2bf(acc.z * dd); pk.w = f2bf(acc.w * dd);
    G[(size_t)node * 16 + cq] = pk;
}

// ---- KF: gather(G1) + bias + relu + gemm(W2) + dinv-fold -> G2 (bf16) ----
// 4 waves/block, 64 nodes/block in 16 double-buffered iterations.
__global__ __launch_bounds__(256) void gather_gemm(
        const int* __restrict__ next, const int* __restrict__ esrc,
        const float* __restrict__ dinv, const unsigned* __restrict__ G1,
        const float* __restrict__ b1, const float* __restrict__ W2,
        unsigned* __restrict__ G2) {
    __shared__ float W2s[64 * 64];        // [k][c], lane-stride-1: conflict-free
    __shared__ float h1buf[2][4][64];
    int tid = threadIdx.x;
    {
        const float4* W4 = (const float4*)W2;
        float4* Ws4 = (float4*)W2s;
        #pragma unroll
        for (int i = tid; i < 1024; i += 256) Ws4[i] = W4[i];
    }
    int w = tid >> 6, lane = tid & 63, half = lane >> 5, m = lane & 31;
    #pragma unroll 1
    for (int it = 0; it < 16; ++it) {
        int node = blockIdx.x * 64 + it * 4 + w;
        bool valid = node < NN;
        float dd = 0.f;
        if (valid) {
            int j0 = node ? next[node - 1] : 0;
            int e1 = next[node];
            float ax = 0.f, ay = 0.f;
            int j = j0 + half;
            for (; j + 6 < e1; j += 8) {
                int s0 = esrc[j], s1 = esrc[j + 2], s2 = esrc[j + 4], s3 = esrc[j + 6];
                unsigned u0 = G1[s0 * 32 + m];
                unsigned u1 = G1[s1 * 32 + m];
                unsigned u2 = G1[s2 * 32 + m];
                unsigned u3 = G1[s3 * 32 + m];
                ax += __uint_as_float(u0 << 16) + __uint_as_float(u1 << 16)
                    + __uint_as_float(u2 << 16) + __uint_as_float(u3 << 16);
                ay += __uint_as_float(u0 & 0xffff0000u) + __uint_as_float(u1 & 0xffff0000u)
                    + __uint_as_float(u2 & 0xffff0000u) + __uint_as_float(u3 & 0xffff0000u);
            }
            for (; j < e1; j += 2) {
                unsigned u = G1[esrc[j] * 32 + m];
                ax += __uint_as_float(u << 16);
                ay += __uint_as_float(u & 0xffff0000u);
            }
            ax += __shfl_xor(ax, 32);
            ay += __shfl_xor(ay, 32);
            dd = dinv[node];
            unsigned us = G1[node * 32 + m];        // self: g*dd = h*dinv^2
            ax += __uint_as_float(us << 16);
            ay += __uint_as_float(us & 0xffff0000u);
            float2 bb = ((const float2*)b1)[m];
            float hx = fmaxf(fmaf(ax, dd, bb.x), 0.f);
            float hy = fmaxf(fmaf(ay, dd, bb.y), 0.f);
            if (half == 0) {
                h1buf[it & 1][w][2 * m]     = hx;
                h1buf[it & 1][w][2 * m + 1] = hy;
            }
        }
        __syncthreads();
        if (valid) {
            const float* h1 = h1buf[it & 1][w];
            float acc = 0.f;
            #pragma unroll
            for (int k = 0; k < 64; ++k)
                acc = fmaf(h1[k], W2s[k * 64 + lane], acc);   // h1: LDS broadcast
            float g  = acc * dd;
            float go = __shfl_down(g, 1);
            if (!(lane & 1))
                G2[node * 32 + (lane >> 1)] =
                    (unsigned)f2bf(g) | ((unsigned)f2bf(go) << 16);
        }
    }
}

// ---- KG: gather(G2) + bias + relu + FC(Wfc) + bfc -> out ----
__global__ __launch_bounds__(256) void gather_fc(
        const int* __restrict__ next, const int* __restrict__ esrc,
        const float* __restrict__ dinv, const unsigned* __restrict__ G2,
        const float* __restrict__ b2, const float* __restrict__ Wfc,
        const float* __restrict__ bfc, float* __restrict__ out) {
    __shared__ float Wfs[64 * 16];        // [k][c]
    __shared__ float h2buf[2][4][64];
    int tid = threadIdx.x;
    {
        const float4* W4 = (const float4*)Wfc;
        ((float4*)Wfs)[tid] = W4[tid];    // 256 float4 = 1024 floats
    }
    int w = tid >> 6, lane = tid & 63, half = lane >> 5, m = lane & 31;
    #pragma unroll 1
    for (int it = 0; it < 16; ++it) {
        int node = blockIdx.x * 64 + it * 4 + w;
        bool valid = node < NN;
        if (valid) {
            int j0 = node ? next[node - 1] : 0;
            int e1 = next[node];
            float ax = 0.f, ay = 0.f;
            int j = j0 + half;
            for (; j + 6 < e1; j += 8) {
                int s0 = esrc[j], s1 = esrc[j + 2], s2 = esrc[j + 4], s3 = esrc[j + 6];
                unsigned u0 = G2[s0 * 32 + m];
                unsigned u1 = G2[s1 * 32 + m];
                unsigned u2 = G2[s2 * 32 + m];
                unsigned u3 = G2[s3 * 32 + m];
                ax += __uint_as_float(u0 << 16) + __uint_as_float(u1 << 16)
                    + __uint_as_float(u2 << 16) + __uint_as_float(u3 << 16);
                ay += __uint_as_float(u0 & 0xffff0000u) + __uint_as_float(u1 & 0xffff0000u)
                    + __uint_as_float(u2 & 0xffff0000u) + __uint_as_float(u3 & 0xffff0000u);
            }
            for (; j < e1; j += 2) {
                unsigned u = G2[esrc[j] * 32 + m];
                ax += __uint_as_float(u << 16);
                ay += __uint_as_float(u & 0xffff0000u);
            }
            ax += __shfl_xor(ax, 32);
            ay += __shfl_xor(ay, 32);
            float dd = dinv[node];
            unsigned us = G2[node * 32 + m];
            ax += __uint_as_float(us << 16);
            ay += __uint_as_float(us & 0xffff0000u);
            float2 bb = ((const float2*)b2)[m];
            float hx = fmaxf(fmaf(ax, dd, bb.x), 0.f);
            float hy = fmaxf(fmaf(ay, dd, bb.y), 0.f);
            if (half == 0) {
                h2buf[it & 1][w][2 * m]     = hx;
                h2buf[it & 1][w][2 * m + 1] = hy;
            }
        }
        __syncthreads();
        if (valid) {
            const float* h2 = h2buf[it & 1][w];
            int cq = lane & 15, q = lane >> 4;       // split-k over 4 groups
            float acc = 0.f;
            #pragma unroll
            for (int kk = 0; kk < 16; ++kk) {
                int k = q * 16 + kk;
                acc = fmaf(h2[k], Wfs[k * 16 + cq], acc);
            }
            acc += __shfl_xor(acc, 16);
            acc += __shfl_xor(acc, 32);
            if (q == 0) out[node * 16 + cq] = acc + bfc[cq];
        }
    }
}

extern "C" void kernel_launch(void* const* d_in, const int* in_sizes, int n_in,
                              void* d_out, int out_size, void* d_ws, size_t ws_size,
                              hipStream_t stream) {
    const float* x   = (const float*)d_in[0];
    const int*   ei  = (const int*)d_in[1];
    const float* W1  = (const float*)d_in[2];
    const float* b1  = (const float*)d_in[3];
    const float* W2  = (const float*)d_in[4];
    const float* b2  = (const float*)d_in[5];
    const float* Wfc = (const float*)d_in[6];
    const float* bfc = (const float*)d_in[7];
    float* out = (float*)d_out;

    const int* src = ei;
    const int* dst = ei + NE;

    // ws: dinv[NN]f | bbase[513] | next[NN] | C[(196+1)*512] | esrc[NE] | pairs[NE]
    //     | G1[NN*32 u] | G2[NN*32 u]    (~39.6 MB)
    float*    dinv  = (float*)d_ws;
    int*      bbase = (int*)(dinv + NN);
    int*      next  = bbase + NBP + 1;
    int*      C     = next + NN;
    int*      esrc  = C + (NCHUNK + 1) * NBP;
    int*      pairs = esrc + NE;
    unsigned* G1    = (unsigned*)(pairs + NE);
    unsigned* G2    = G1 + (size_t)NN * 32;

    // ---- CSR build (deterministic two-pass counting sort, 4 dispatches) ----
    hist_rows<<<NCHUNK, 256, 0, stream>>>(dst, C);
    offsets_k<<<1, 512, 0, stream>>>(C, bbase);
    place_k<<<NCHUNK, 512, 0, stream>>>(src, dst, C, pairs);
    bkt_csr<<<NB, 256, 0, stream>>>(pairs, bbase, next, dinv, esrc);

    // ---- fused pipeline (3 dispatches) ----
    gemm64g<<<NN / 16, 256, 0, stream>>>(x, W1, dinv, (ushort4*)G1, NN);
    gather_gemm<<<(NN + 63) / 64, 256, 0, stream>>>(next, esrc, dinv, G1, b1, W2, G2);
    gather_fc<<<(NN + 63) / 64, 256, 0, stream>>>(next, esrc, dinv, G2, b2, Wfc, bfc, out);
}

// Round 7
// 333.805 us; speedup vs baseline: 1.0543x; 1.0543x over previous
//
#include <hip/hip_runtime.h>

#define NN 100000
#define NE 1600000
#define NB 391              // ceil(NN/256) node-buckets of 256 dst nodes
#define NBP 512             // padded bucket count (pow2)
#define CHUNK 4096
#define NCHUNK 391          // ceil(NE/CHUNK)

static __device__ __forceinline__ unsigned short f2bf(float f) {
    unsigned u = __float_as_uint(f);
    u += 0x7fffu + ((u >> 16) & 1u);   // RNE
    return (unsigned short)(u >> 16);
}

// ---- KA: per-chunk bucket histogram rows (block-owned, no global atomics) ----
__global__ __launch_bounds__(256) void hist_rows(const int* __restrict__ dst,
                                                 int* __restrict__ C) {
    __shared__ int h[NBP];
    int t = threadIdx.x;
    h[t] = 0; h[t + 256] = 0;
    __syncthreads();
    int base = blockIdx.x * CHUNK;
    int end = min(base + CHUNK, NE);
    for (int e = base + t; e < end; e += 256) atomicAdd(&h[dst[e] >> 8], 1);
    __syncthreads();
    C[blockIdx.x * NBP + t] = h[t];
    C[blockIdx.x * NBP + t + 256] = h[t + 256];
}

// ---- KB: single block: bucket totals -> bbase; rewrite C rows to global offsets ----
__global__ __launch_bounds__(512) void offsets_k(int* __restrict__ C,
                                                 int* __restrict__ bbase) {
    __shared__ int buf[2][512];
    int t = threadIdx.x;
    int tot = 0;
    for (int c0 = 0; c0 < NCHUNK; c0 += 8) {
        int v[8];
        #pragma unroll
        for (int j = 0; j < 8; ++j) {
            int cc = c0 + j;
            v[j] = (cc < NCHUNK) ? C[cc * NBP + t] : 0;   // 8 loads in flight
        }
        #pragma unroll
        for (int j = 0; j < 8; ++j) tot += v[j];
    }
    int pi = 0; buf[0][t] = tot; __syncthreads();
    for (int off = 1; off < 512; off <<= 1) {
        int add = (t >= off) ? buf[pi][t - off] : 0;
        buf[1 - pi][t] = buf[pi][t] + add; pi ^= 1; __syncthreads();
    }
    int ex = buf[pi][t] - tot;
    bbase[t] = ex;
    if (t == 511) bbase[512] = buf[pi][511];   // == NE
    int run = ex;
    for (int c0 = 0; c0 < NCHUNK; c0 += 8) {
        int v[8];
        #pragma unroll
        for (int j = 0; j < 8; ++j) {
            int cc = c0 + j;
            v[j] = (cc < NCHUNK) ? C[cc * NBP + t] : 0;
        }
        #pragma unroll
        for (int j = 0; j < 8; ++j) {
            int cc = c0 + j;
            if (cc < NCHUNK) { C[cc * NBP + t] = run; run += v[j]; }
        }
    }
}

// ---- KC: placement via exclusive chunk regions — direct scatter, no scan/search ----
__global__ __launch_bounds__(256) void place_k(const int* __restrict__ src,
                                               const int* __restrict__ dst,
                                               const int* __restrict__ C,
                                               int* __restrict__ pairs) {
    __shared__ int lnext[NBP];
    int t = threadIdx.x;
    int c = blockIdx.x;
    lnext[t]       = C[c * NBP + t];        // this chunk's exclusive region starts
    lnext[t + 256] = C[c * NBP + t + 256];
    __syncthreads();
    int base = c * CHUNK;
    int end = min(base + CHUNK, NE);
    for (int e = base + t; e < end; e += 256) {
        int d = dst[e];
        int p = atomicAdd(&lnext[d >> 8], 1);
        pairs[p] = src[e] | ((d & 255) << 17);   // lines are block-exclusive
    }
}

// ---- KD: per-bucket CSR build + dinv ----
__global__ __launch_bounds__(256) void bkt_csr(const int* __restrict__ pairs,
                                               const int* __restrict__ base,
                                               int* __restrict__ next,
                                               float* __restrict__ dinv,
                                               int* __restrict__ esrc) {
    __shared__ int cnt[256];
    __shared__ int sbuf[2][256];
    __shared__ int nxt[256];
    int b = blockIdx.x;
    int e0 = base[b], e1 = base[b + 1];
    int t = threadIdx.x;
    cnt[t] = 0;
    __syncthreads();
    for (int i = e0 + t; i < e1; i += 256) atomicAdd(&cnt[pairs[i] >> 17], 1);
    __syncthreads();
    int v = cnt[t];
    int pi = 0; sbuf[0][t] = v; __syncthreads();
    for (int off = 1; off < 256; off <<= 1) {
        int add = (t >= off) ? sbuf[pi][t - off] : 0;
        sbuf[1 - pi][t] = sbuf[pi][t] + add; pi ^= 1; __syncthreads();
    }
    int incl = sbuf[pi][t];
    int node = b * 256 + t;
    if (node < NN) {
        next[node] = e0 + incl;
        dinv[node] = rsqrtf((float)v + 1.0f);
    }
    nxt[t] = e0 + incl - v;
    __syncthreads();
    for (int i = e0 + t; i < e1; i += 256) {
        int w = pairs[i];
        int p = atomicAdd(&nxt[w >> 17], 1);
        esrc[p] = w & 0x1FFFF;
    }
}

// ---- KE: GEMM [n,64]@[64,64] -> bf16 g = acc*dinv ----
__global__ __launch_bounds__(256) void gemm64g(const float* __restrict__ X,
                                               const float* __restrict__ W,
                                               const float* __restrict__ dinv,
                                               ushort4* __restrict__ G, int n) {
    __shared__ float4 Ws[64][16];
    __shared__ float  Xs[16][68];
    int tid = threadIdx.x;
    const float4* W4 = (const float4*)W;
    #pragma unroll
    for (int i = tid; i < 64 * 16; i += 256) Ws[i >> 4][i & 15] = W4[i];
    {
        int rr = tid >> 4, q = tid & 15;
        int node = blockIdx.x * 16 + rr;
        float4 v = ((const float4*)(X + (size_t)node * 64))[q];
        *(float4*)&Xs[rr][q * 4] = v;
    }
    __syncthreads();
    int r = tid >> 4, cq = tid & 15;
    float4 acc = {0.f, 0.f, 0.f, 0.f};
    #pragma unroll
    for (int k = 0; k < 64; ++k) {
        float x  = Xs[r][k];
        float4 w = Ws[k][cq];
        acc.x += x * w.x; acc.y += x * w.y; acc.z += x * w.z; acc.w += x * w.w;
    }
    int node = blockIdx.x * 16 + r;
    float dd = dinv[node];
    ushort4 pk;
    pk.x = f2bf(acc.x * dd); pk.y = f2bf(acc.y * dd);
    pk.z = f2bf(acc.z * dd); pk.w = f2bf(acc.w * dd);
    G[(size_t)node * 16 + cq] = pk;
}

// ---- KF: fused gather (bf16 operand): agg + self + bias + relu ----
// one independent wave per dst node — NO cross-wave barriers (R6 lesson)
__global__ __launch_bounds__(256) void gather_bf16(
        const int* __restrict__ next, const int* __restrict__ esrc,
        const float* __restrict__ dinv, const unsigned* __restrict__ G,
        const float* __restrict__ b, float* __restrict__ outH, int n) {
    int node = (int)((blockIdx.x * blockDim.x + threadIdx.x) >> 6);
    if (node >= n) return;
    int lane = threadIdx.x & 63;
    int half = lane >> 5, m = lane & 31;
    int j0 = node ? next[node - 1] : 0;
    int e1 = next[node];
    float ax = 0.f, ay = 0.f;
    int j = j0 + half;
    for (; j + 6 < e1; j += 8) {
        int s0 = esrc[j], s1 = esrc[j + 2], s2 = esrc[j + 4], s3 = esrc[j + 6];
        unsigned u0 = G[s0 * 32 + m];
        unsigned u1 = G[s1 * 32 + m];
        unsigned u2 = G[s2 * 32 + m];
        unsigned u3 = G[s3 * 32 + m];
        ax += __uint_as_float(u0 << 16) + __uint_as_float(u1 << 16)
            + __uint_as_float(u2 << 16) + __uint_as_float(u3 << 16);
        ay += __uint_as_float(u0 & 0xffff0000u) + __uint_as_float(u1 & 0xffff0000u)
            + __uint_as_float(u2 & 0xffff0000u) + __uint_as_float(u3 & 0xffff0000u);
    }
    for (; j < e1; j += 2) {
        unsigned u = G[esrc[j] * 32 + m];
        ax += __uint_as_float(u << 16);
        ay += __uint_as_float(u & 0xffff0000u);
    }
    ax += __shfl_xor(ax, 32);
    ay += __shfl_xor(ay, 32);
    if (half == 0) {
        float dd = dinv[node];
        unsigned us = G[node * 32 + m];          // self: g*dd = h*dinv^2
        ax += __uint_as_float(us << 16);
        ay += __uint_as_float(us & 0xffff0000u);
        float2 bb = ((const float2*)b)[m];
        float2 o;
        o.x = fmaxf(fmaf(ax, dd, bb.x), 0.f);
        o.y = fmaxf(fmaf(ay, dd, bb.y), 0.f);
        ((float2*)(outH + (size_t)node * 64))[m] = o;
    }
}

// ---- KG: FC head [n,64]@[64,16] + b ----
__global__ __launch_bounds__(256) void gemmfc(const float* __restrict__ X,
                                              const float* __restrict__ W,
                                              const float* __restrict__ b,
                                              float* __restrict__ out, int n) {
    __shared__ float Ws[64][16];
    __shared__ float Xs[16][65];
    int tid = threadIdx.x;
    #pragma unroll
    for (int i = tid; i < 64 * 16; i += 256) Ws[i >> 4][i & 15] = W[i];
    #pragma unroll
    for (int i = tid; i < 16 * 64; i += 256) {
        int rr = i >> 6, cc = i & 63;
        int nn = blockIdx.x * 16 + rr;
        Xs[rr][cc] = (nn < n) ? X[nn * 64 + cc] : 0.f;
    }
    __syncthreads();
    int col = tid & 15, r = tid >> 4;
    int node = blockIdx.x * 16 + r;
    if (node >= n) return;
    float acc = b[col];
    #pragma unroll
    for (int k = 0; k < 64; ++k) acc += Xs[r][k] * Ws[k][col];
    out[node * 16 + col] = acc;
}

extern "C" void kernel_launch(void* const* d_in, const int* in_sizes, int n_in,
                              void* d_out, int out_size, void* d_ws, size_t ws_size,
                              hipStream_t stream) {
    const float* x   = (const float*)d_in[0];
    const int*   ei  = (const int*)d_in[1];
    const float* W1  = (const float*)d_in[2];
    const float* b1  = (const float*)d_in[3];
    const float* W2  = (const float*)d_in[4];
    const float* b2  = (const float*)d_in[5];
    const float* Wfc = (const float*)d_in[6];
    const float* bfc = (const float*)d_in[7];
    float* out = (float*)d_out;

    const int* src = ei;
    const int* dst = ei + NE;

    // ws: dinv[NN] | bbase[513] | next[NN] | C[(391+1)*512] | esrc[NE]
    //     | G[NN*32 u, 12.8MB] | bufB[NN*64 f32, 25.6MB]  (~46.5 MB)
    // pairs aliases bufB (consumed by bkt_csr before gather-1 writes bufB)
    float*    dinv  = (float*)d_ws;
    int*      bbase = (int*)(dinv + NN);
    int*      next  = bbase + NBP + 1;
    int*      C     = next + NN;
    int*      esrc  = C + (NCHUNK + 1) * NBP;
    unsigned* G     = (unsigned*)(esrc + NE);
    float*    bufB  = (float*)(G + (size_t)NN * 32);
    int*      pairs = (int*)bufB;

    // ---- CSR build (deterministic offsets, 4 dispatches) ----
    hist_rows<<<NCHUNK, 256, 0, stream>>>(dst, C);
    offsets_k<<<1, 512, 0, stream>>>(C, bbase);
    place_k<<<NCHUNK, 256, 0, stream>>>(src, dst, C, pairs);
    bkt_csr<<<NB, 256, 0, stream>>>(pairs, bbase, next, dinv, esrc);

    // ---- layer 1 ----
    gemm64g<<<NN / 16, 256, 0, stream>>>(x, W1, dinv, (ushort4*)G, NN);
    gather_bf16<<<(NN * 64) / 256, 256, 0, stream>>>(next, esrc, dinv, G, b1, bufB, NN);

    // ---- layer 2 ----
    gemm64g<<<NN / 16, 256, 0, stream>>>(bufB, W2, dinv, (ushort4*)G, NN);
    gather_bf16<<<(NN * 64) / 256, 256, 0, stream>>>(next, esrc, dinv, G, b2, bufB, NN);

    // ---- FC head ----
    gemmfc<<<NN / 16, 256, 0, stream>>>(bufB, Wfc, bfc, out, NN);
}